// Round 1
// 913.048 us; speedup vs baseline: 1.0019x; 1.0019x over previous
//
#include <hip/hip_runtime.h>

// ItemEncoder: out[t, j] = sum_k U[ids[t], k] * W[j, k] + b[j]
//   ids: int32 [12800], U: fp32 [100000, 2000], W: fp32 [8, 2000], b: fp32 [8]
// HBM-bound cold: 102.4 MB gathered rows @ ~6.3 TB/s -> ~16.5 us floor; on
// warm replays the ~97 MB unique-row set is L3-resident and the LDS pipe
// (W re-reads) becomes co-binding. This version amortizes each W LDS read
// over FOUR tokens (was two): 32 -> 16 ds_read_b128 per token, halving the
// per-CU LDS time (~8 -> ~4 us), and doubles VMEM MLP (32 loads in flight
// per lane). x[4][8] float4 = 128 VGPR + 32 acc fits the 256-VGPR /
// 2-waves-per-SIMD budget; occupancy unchanged (LDS-limited 2 blocks/CU).
//
// W staged once per block in LDS ([8][512] float4, 64 KB, pad zeroed ->
// conflict-free ds_read_b128: j uniform across wave, k4 = lane + i*64).
// Reduction per token: fold 8 accs -> 1 while butterflying (xor 1,2,4 with
// select-before-shuffle), then 3 octet butterflies = 10 shuffles/token.
// Final lane->j mapping is bit-reversed(lane&7).

#define IN_DIM   2000
#define IN_DIM4  500      // float4s per row
#define PAD_DIM4 512      // padded float4s per W row in LDS
#define OUT_DIM  8
#define GROUP    4        // tokens per wave-iteration sharing each W read

__global__ __launch_bounds__(256, 2)
void item_encoder_kernel(const int* __restrict__ ids,
                         const float* __restrict__ U,
                         const float* __restrict__ W,
                         const float* __restrict__ bias,
                         float* __restrict__ out,
                         int T)
{
    __shared__ float4 wlds[OUT_DIM * PAD_DIM4];   // 64 KB

    const int tid = threadIdx.x;

    // --- stage W into padded LDS (zero the pad) -------------------------
    const float4* Wv = (const float4*)W;
    #pragma unroll
    for (int i = 0; i < 16; ++i) {
        int d  = tid + i * 256;
        int j  = d >> 9;
        int k4 = d & 511;
        float4 v = make_float4(0.f, 0.f, 0.f, 0.f);
        if (k4 < IN_DIM4) v = Wv[j * IN_DIM4 + k4];
        wlds[d] = v;
    }
    __syncthreads();

    const int lane    = tid & 63;
    const int wave    = tid >> 6;
    const int wave_id = blockIdx.x * 4 + wave;
    const int nwaves  = gridDim.x * 4;

    // j index this lane will own after the fold-reduce (bit-reversed low-3)
    const int jmap = ((lane & 1) << 2) | (lane & 2) | ((lane >> 2) & 1);
    const float bj = bias[jmap];   // tiny, cache-resident broadcast

    for (int t0 = wave_id; t0 < T; t0 += GROUP * nwaves) {
        int  tt[GROUP];
        bool has[GROUP];
        int  idg[GROUP];
        #pragma unroll
        for (int g = 0; g < GROUP; ++g) {
            tt[g]  = t0 + g * nwaves;
            has[g] = (tt[g] < T);                 // has[0] always true
            idg[g] = has[g] ? ids[tt[g]] : ids[t0];
        }

        // pull all four rows: 32 coalesced dwordx4 per lane, all in flight
        float4 x[GROUP][8];
        #pragma unroll
        for (int g = 0; g < GROUP; ++g) {
            const float4* r = (const float4*)(U + (size_t)idg[g] * IN_DIM);
            #pragma unroll
            for (int i = 0; i < 8; ++i) {
                const int  k4 = lane + i * 64;
                x[g][i] = (k4 < IN_DIM4) ? r[k4]
                                         : make_float4(0.f, 0.f, 0.f, 0.f);
            }
        }

        float acc[GROUP][OUT_DIM];
        #pragma unroll
        for (int g = 0; g < GROUP; ++g)
            #pragma unroll
            for (int j = 0; j < OUT_DIM; ++j) acc[g][j] = 0.f;

        // each W LDS read feeds FOUR tokens
        #pragma unroll
        for (int i = 0; i < 8; ++i) {
            const int k4 = lane + i * 64;
            #pragma unroll
            for (int j = 0; j < OUT_DIM; ++j) {
                const float4 w = wlds[j * PAD_DIM4 + k4];
                #pragma unroll
                for (int g = 0; g < GROUP; ++g) {
                    acc[g][j] += x[g][i].x * w.x + x[g][i].y * w.y
                               + x[g][i].z * w.z + x[g][i].w * w.w;
                }
            }
        }

        // ---- fold-reduce per token: 8 accs -> 1 value/lane -------------
        float v[GROUP];
        #pragma unroll
        for (int g = 0; g < GROUP; ++g) {
            float a4[4];
            #pragma unroll
            for (int m = 0; m < 4; ++m) {
                float s = (lane & 1) ? acc[g][m] : acc[g][m + 4];
                float k = (lane & 1) ? acc[g][m + 4] : acc[g][m];
                a4[m] = k + __shfl_xor(s, 1, 64);
            }
            float a2[2];
            #pragma unroll
            for (int m = 0; m < 2; ++m) {
                float s = (lane & 2) ? a4[m] : a4[m + 2];
                float k = (lane & 2) ? a4[m + 2] : a4[m];
                a2[m] = k + __shfl_xor(s, 2, 64);
            }
            float s = (lane & 4) ? a2[0] : a2[1];
            float k = (lane & 4) ? a2[1] : a2[0];
            float vv = k + __shfl_xor(s, 4, 64);
            vv += __shfl_xor(vv, 8, 64);
            vv += __shfl_xor(vv, 16, 64);
            vv += __shfl_xor(vv, 32, 64);
            v[g] = vv;
        }

        if (lane < OUT_DIM) {
            #pragma unroll
            for (int g = 0; g < GROUP; ++g) {
                if (has[g])
                    out[(size_t)tt[g] * OUT_DIM + jmap] = v[g] + bj;
            }
        }
    }
}

extern "C" void kernel_launch(void* const* d_in, const int* in_sizes, int n_in,
                              void* d_out, int out_size, void* d_ws, size_t ws_size,
                              hipStream_t stream)
{
    const int*   ids  = (const int*)d_in[0];     // [B*L]
    const float* U    = (const float*)d_in[1];   // [NTOKEN, 2000]
    const float* W    = (const float*)d_in[2];   // [8, 2000]
    const float* bias = (const float*)d_in[3];   // [8]
    float*       out  = (float*)d_out;           // [B*L, 8]

    const int T = in_sizes[0];                   // 12800 tokens

    // 512 blocks x 256 thr: 2 blocks/CU (LDS-limited), all co-resident,
    // 2048 waves; each wave runs exactly 2 group-iterations (4 + ~2 tokens).
    item_encoder_kernel<<<dim3(512), dim3(256), 0, stream>>>(ids, U, W, bias, out, T);
}